// Round 5
// baseline (1224.353 us; speedup 1.0000x reference)
//
#include <hip/hip_runtime.h>
#include <math.h>

#define MARGIN 0.4f
#define EPSF   1e-3f
#define SCALE  64.0f
#define EPT    16     // float4s per thread
#define BLK    256    // threads per block

typedef float vfloat4 __attribute__((ext_vector_type(4)));

// Single kernel: R3's interleaved streaming (grid-wide contiguous window per
// unroll step — the proven 5.85 TB/s pattern), then the LAST block to finish
// (device-scope atomic in d_ws) performs the stats + target-element fixup.
__global__ __launch_bounds__(BLK)
void adaface_stream_fixup_kernel(const float* __restrict__ in_s,
                                 const float* __restrict__ norms,
                                 const int* __restrict__ labels,
                                 float* __restrict__ out_s,
                                 long n4, long n, int B, int C,
                                 unsigned int* __restrict__ counter,
                                 int nblocks) {
    const vfloat4* __restrict__ in  = (const vfloat4*)in_s;
    vfloat4* __restrict__ out = (vfloat4*)out_s;

    int  tid = threadIdx.x;
    long nthreads = (long)gridDim.x * BLK;
    long i = (long)blockIdx.x * BLK + tid;

    // ---- streaming phase (identical mapping to R3) ----
#pragma unroll
    for (int j = 0; j < EPT; ++j) {
        long k = i + (long)j * nthreads;
        if (k < n4) {
            vfloat4 v = __builtin_nontemporal_load(&in[k]);
            v *= SCALE;
            __builtin_nontemporal_store(v, &out[k]);
        }
    }
    // scalar tail (empty here: n % 4 == 0)
    for (long k = n4 * 4 + i; k < n; k += nthreads) {
        out_s[k] = in_s[k] * SCALE;
    }

    // ---- last-block-done fixup ----
    __shared__ int s_last;
    __threadfence();                       // release: streaming writes visible
    if (tid == 0) {
        unsigned int old = atomicAdd(counter, 1u);
        s_last = (old == (unsigned int)(nblocks - 1)) ? 1 : 0;
    }
    __syncthreads();
    if (!s_last) return;
    __threadfence();                       // acquire: see all blocks' writes

    // stats over B rows: 256 threads x 4 rows
    __shared__ float ra[4], rb[4];
    __shared__ float sm[3];                // mean, std, cnt
    float lsn[4]; int llab[4]; bool lp[4];
    float lsum = 0.0f, lcnt = 0.0f;
#pragma unroll
    for (int q = 0; q < 4; ++q) {
        int r = tid + q * BLK;
        bool p = false; float s = 0.0f; int lb = -1;
        if (r < B) {
            lb = labels[r];
            p = (lb != -1);
            s = fminf(fmaxf(norms[r], 1e-3f), 100.0f);
        }
        lp[q] = p; lsn[q] = s; llab[q] = lb;
        if (p) { lsum += s; lcnt += 1.0f; }
    }
    int lane = tid & 63, wv = tid >> 6;
    for (int off = 32; off >= 1; off >>= 1) {
        lsum += __shfl_down(lsum, off);
        lcnt += __shfl_down(lcnt, off);
    }
    if (lane == 0) { ra[wv] = lsum; rb[wv] = lcnt; }
    __syncthreads();
    if (tid == 0) {
        float s = ra[0] + ra[1] + ra[2] + ra[3];
        float c = rb[0] + rb[1] + rb[2] + rb[3];
        sm[0] = s / c; sm[2] = c;
    }
    __syncthreads();
    float mean = sm[0];
    float lvar = 0.0f;
#pragma unroll
    for (int q = 0; q < 4; ++q) {
        if (lp[q]) { float d = lsn[q] - mean; lvar += d * d; }
    }
    for (int off = 32; off >= 1; off >>= 1) lvar += __shfl_down(lvar, off);
    if (lane == 0) ra[wv] = lvar;
    __syncthreads();
    if (tid == 0) {
        float v = ra[0] + ra[1] + ra[2] + ra[3];
        sm[1] = sqrtf(v / (sm[2] - 1.0f));
    }
    __syncthreads();
    float stdv = sm[1];

    // patch the target element of each positive row
#pragma unroll
    for (int q = 0; q < 4; ++q) {
        int r = tid + q * BLK;
        if (r < B && lp[q]) {
            float ms  = (lsn[q] - mean) / (stdv + EPSF);
            long  idx = (long)r * C + llab[q];
            float x   = in_s[idx];
            float th  = acosf(x) - MARGIN * ms;
            th = fminf(fmaxf(th, EPSF), (float)M_PI - EPSF);
            out_s[idx] = (cosf(th) - (MARGIN + MARGIN * ms)) * SCALE;
        }
    }
}

extern "C" void kernel_launch(void* const* d_in, const int* in_sizes, int n_in,
                              void* d_out, int out_size, void* d_ws, size_t ws_size,
                              hipStream_t stream) {
    const float* logits = (const float*)d_in[0];
    const float* norms  = (const float*)d_in[1];
    const int*   labels = (const int*)d_in[2];
    float* out = (float*)d_out;

    int  B = in_sizes[2];          // 1024
    long n = (long)in_sizes[0];    // 102,400,000
    int  C = (int)(n / B);         // 100,000

    long n4 = n / 4;
    long grid_l = (n4 + (long)BLK * EPT - 1) / ((long)BLK * EPT);  // 6250
    int  grid = (int)grid_l;

    unsigned int* counter = (unsigned int*)d_ws;
    hipMemsetAsync(counter, 0, sizeof(unsigned int), stream);

    adaface_stream_fixup_kernel<<<grid, BLK, 0, stream>>>(
        logits, norms, labels, out, n4, n, B, C, counter, grid);
}

// Round 6
// 146.143 us; speedup vs baseline: 8.3778x; 8.3778x over previous
//
#include <hip/hip_runtime.h>
#include <math.h>

#define MARGIN 0.4f
#define EPSF   1e-3f
#define SCALE  64.0f
#define EPT    16     // float4s per thread
#define BLK    256    // threads per block

typedef float vfloat4 __attribute__((ext_vector_type(4)));

// Kernel 1: streaming (R3's proven interleaved mapping) + ONE extra block
// (blockIdx == gridDim-1) that computes the stats and per-row corrected
// values into a d_ws table, reading only inputs (no ordering hazard).
__global__ __launch_bounds__(BLK)
void adaface_stream_stats_kernel(const float* __restrict__ in_s,
                                 const float* __restrict__ norms,
                                 const int* __restrict__ labels,
                                 float* __restrict__ out_s,
                                 float* __restrict__ table,
                                 long n4, long n, int B, int C) {
    int tid = threadIdx.x;

    if (blockIdx.x == gridDim.x - 1) {
        // ---- stats block: mean/std over positive rows, corrected values ----
        __shared__ float ra[4], rb[4];
        __shared__ float sm[3];            // mean, std, cnt
        float lsn[4]; int llab[4]; bool lp[4];
        float lsum = 0.0f, lcnt = 0.0f;
#pragma unroll
        for (int q = 0; q < 4; ++q) {
            int r = tid + q * BLK;
            bool p = false; float s = 0.0f; int lb = -1;
            if (r < B) {
                lb = labels[r];
                p = (lb != -1);
                s = fminf(fmaxf(norms[r], 1e-3f), 100.0f);
            }
            lp[q] = p; lsn[q] = s; llab[q] = lb;
            if (p) { lsum += s; lcnt += 1.0f; }
        }
        int lane = tid & 63, wv = tid >> 6;
        for (int off = 32; off >= 1; off >>= 1) {
            lsum += __shfl_down(lsum, off);
            lcnt += __shfl_down(lcnt, off);
        }
        if (lane == 0) { ra[wv] = lsum; rb[wv] = lcnt; }
        __syncthreads();
        if (tid == 0) {
            float s = ra[0] + ra[1] + ra[2] + ra[3];
            float c = rb[0] + rb[1] + rb[2] + rb[3];
            sm[0] = s / c; sm[2] = c;
        }
        __syncthreads();
        float mean = sm[0];
        float lvar = 0.0f;
#pragma unroll
        for (int q = 0; q < 4; ++q) {
            if (lp[q]) { float d = lsn[q] - mean; lvar += d * d; }
        }
        for (int off = 32; off >= 1; off >>= 1) lvar += __shfl_down(lvar, off);
        if (lane == 0) ra[wv] = lvar;
        __syncthreads();
        if (tid == 0) {
            float v = ra[0] + ra[1] + ra[2] + ra[3];
            sm[1] = sqrtf(v / (sm[2] - 1.0f));
        }
        __syncthreads();
        float stdv = sm[1];

#pragma unroll
        for (int q = 0; q < 4; ++q) {
            int r = tid + q * BLK;
            if (r < B) {
                float val = 0.0f;
                if (lp[q]) {
                    float ms  = (lsn[q] - mean) / (stdv + EPSF);
                    long  idx = (long)r * C + llab[q];
                    float x   = in_s[idx];
                    float th  = acosf(x) - MARGIN * ms;
                    th = fminf(fmaxf(th, EPSF), (float)M_PI - EPSF);
                    val = (cosf(th) - (MARGIN + MARGIN * ms)) * SCALE;
                }
                table[r] = val;
            }
        }
        return;
    }

    // ---- streaming blocks: identical mapping to R3 ----
    const vfloat4* __restrict__ in  = (const vfloat4*)in_s;
    vfloat4* __restrict__ out = (vfloat4*)out_s;
    long nthreads = (long)(gridDim.x - 1) * BLK;
    long i = (long)blockIdx.x * BLK + tid;

#pragma unroll
    for (int j = 0; j < EPT; ++j) {
        long k = i + (long)j * nthreads;
        if (k < n4) {
            vfloat4 v = __builtin_nontemporal_load(&in[k]);
            v *= SCALE;
            __builtin_nontemporal_store(v, &out[k]);
        }
    }
    // scalar tail (empty here: n % 4 == 0)
    for (long k = n4 * 4 + i; k < n; k += nthreads) {
        out_s[k] = in_s[k] * SCALE;
    }
}

// Kernel 2: scatter-only patch — write precomputed values at target columns.
__global__ __launch_bounds__(1024)
void adaface_patch_kernel(const int* __restrict__ labels,
                          const float* __restrict__ table,
                          float* __restrict__ out_s, int B, int C) {
    int r = blockIdx.x * 1024 + threadIdx.x;
    if (r < B) {
        int lab = labels[r];
        if (lab != -1) {
            out_s[(long)r * C + lab] = table[r];
        }
    }
}

extern "C" void kernel_launch(void* const* d_in, const int* in_sizes, int n_in,
                              void* d_out, int out_size, void* d_ws, size_t ws_size,
                              hipStream_t stream) {
    const float* logits = (const float*)d_in[0];
    const float* norms  = (const float*)d_in[1];
    const int*   labels = (const int*)d_in[2];
    float* out   = (float*)d_out;
    float* table = (float*)d_ws;   // B floats

    int  B = in_sizes[2];          // 1024
    long n = (long)in_sizes[0];    // 102,400,000
    int  C = (int)(n / B);         // 100,000

    long n4 = n / 4;
    long sgrid = (n4 + (long)BLK * EPT - 1) / ((long)BLK * EPT);  // 6250
    int  grid = (int)sgrid + 1;    // +1 stats block

    adaface_stream_stats_kernel<<<grid, BLK, 0, stream>>>(
        logits, norms, labels, out, table, n4, n, B, C);

    adaface_patch_kernel<<<(B + 1023) / 1024, 1024, 0, stream>>>(
        labels, table, out, B, C);
}